// Round 7
// baseline (165.329 us; speedup 1.0000x reference)
//
#include <hip/hip_runtime.h>

// Problem constants (from reference)
#define TOTAL_WORDS 10000
#define EMB 100
#define SEQ 80
#define UNITS 64
#define BATCH 16384

// ---------------------------------------------------------------------------
// Register-resident 2-layer SimpleRNN on v_mfma_f32_16x16x16f16, 4-wave
// M-split cooperation (one 16-unit output tile per wave).
//
//  - Block = 4 waves sharing one 16-row batch group; wave w owns output tile
//    mt=w for both layers. 1024 blocks x 4 waves = 4096 waves -> 4 waves/SIMD
//    (R6 had 2): each wave's LDS-latency + MFMA-chain stalls hide under 3
//    other waves from different blocks.
//  - Software pipeline: Wh1*h1(t-1) chain is independent of layer 0 -> its 4
//    MFMAs interleave with layer-0's 4 before the first barrier; only the
//    4-deep Wx1*h0n chain remains after it.
//  - ZERO dynamic register indexing (R5 lesson: runtime-indexed reg arrays
//    demote to scratch, 7.5x regression). Tile identity only affects
//    addresses; all reg-array indices are compile-time.
//  - D-layout == B-layout per lane (16x16x16 f16 MFMA): LDS exchange is
//    lane-aligned uint2 copies, no shuffle/transpose.
//  - lds_barrier() = `s_waitcnt lgkmcnt(0); s_barrier`: LDS-only drain keeps
//    embW/token global prefetches in flight across barriers. Safe buffer
//    reuse: a wave passes a barrier only after its own ds reads completed
//    (lgkmcnt(0)), so no parity buffers needed.
// ---------------------------------------------------------------------------

typedef _Float16 f16x4 __attribute__((ext_vector_type(4)));
typedef __fp16   fp16x2r __attribute__((ext_vector_type(2)));  // cvt_pkrtz ret
typedef float    f32x4 __attribute__((ext_vector_type(4)));

__device__ __forceinline__ float tanh_poly(float x) {
    // odd deg-5: tanh(x) ~ x + x^3*(c3 + c5 x^2); |x| <= ~0.3 -> err < 2e-5
    const float c3 = -0.33333333f, c5 = 0.13333333f;
    float x2 = x * x;
    float p = fmaf(x2, c5, c3);
    float x3 = x * x2;
    return fmaf(x3, p, x);
}

__device__ __forceinline__ f16x4 tanh_pack(f32x4 a) {
    float t0 = tanh_poly(a[0]), t1 = tanh_poly(a[1]);
    float t2 = tanh_poly(a[2]), t3 = tanh_poly(a[3]);
    fp16x2r lo = __builtin_amdgcn_cvt_pkrtz(t0, t1);
    fp16x2r hi = __builtin_amdgcn_cvt_pkrtz(t2, t3);
    f16x4 o;
    o[0] = (_Float16)lo[0]; o[1] = (_Float16)lo[1];
    o[2] = (_Float16)hi[0]; o[3] = (_Float16)hi[1];
    return o;
}

// LDS-only barrier: drains ds ops, leaves global loads in flight.
__device__ __forceinline__ void lds_barrier() {
    asm volatile("s_waitcnt lgkmcnt(0)\n\ts_barrier" ::: "memory");
}

// ------------------- fused prologue: embW + weight packing -----------------
// blocks [0,2500): embW rows (4 per block).
// blocks [2500,2548): pack 48 A-frags (16 layer0 + 32 layer1), 256 f16 each.
// A-frag(mt,kf) element (lane l, j) = W[kf*16 + (l>>4)*4 + j][mt*16 + (l&15)]
__global__ void prep_kernel(const float* __restrict__ emb,
                            const float* __restrict__ Wx0,
                            const float* __restrict__ b0,
                            const float* __restrict__ Wh0,
                            const float* __restrict__ Wx1,
                            const float* __restrict__ Wh1,
                            float* __restrict__ embW,
                            _Float16* __restrict__ wfrags) {
    int b = blockIdx.x;
    if (b < 2500) {
        int v = b * 4 + (threadIdx.x >> 6);
        int u = threadIdx.x & 63;
        float acc = b0[u];
#pragma unroll 10
        for (int k = 0; k < EMB; ++k)
            acc = fmaf(emb[v * EMB + k], Wx0[k * UNITS + u], acc);
        embW[v * UNITS + u] = acc;
    } else {
        int e = (b - 2500) * 256 + threadIdx.x;  // 0..12287
        int f = e >> 8;                          // frag id 0..47
        int rr = e & 255;
        int l = rr >> 2, j = rr & 3;
        int m = l & 15, q = l >> 4;
        int kloc = q * 4 + j;
        float v;
        if (f < 16) {                            // layer0: Wh0
            int mt = f >> 2, kf = f & 3;
            int k = kf * 16 + kloc;
            v = Wh0[k * UNITS + mt * 16 + m];
        } else {                                 // layer1: [Wx1;Wh1], K=128
            int f2 = f - 16;
            int mt = f2 >> 3, kf = f2 & 7;       // kf<4: Wx1, kf>=4: Wh1
            int k = kf * 16 + kloc;
            v = (k < 64) ? Wx1[k * UNITS + mt * 16 + m]
                         : Wh1[(k - 64) * UNITS + mt * 16 + m];
        }
        wfrags[e] = (_Float16)v;
    }
}

// ------------------------------ main kernel --------------------------------
__global__ __launch_bounds__(256, 4) void rnn_mfma_kernel(
    const int*      __restrict__ tokens,   // [BATCH][SEQ]
    const float*    __restrict__ embW,     // [TOTAL_WORDS][UNITS]
    const _Float16* __restrict__ wfrags,   // packed f16 A-frags
    const float*    __restrict__ b1,       // [UNITS]
    const float*    __restrict__ Wout,     // [UNITS]
    const float*    __restrict__ bout,     // [1]
    float*          __restrict__ out) {    // [BATCH]
    const int tid = threadIdx.x;
    const int wv  = tid >> 6;      // wave 0..3: owns output tile mt = wv
    const int l   = tid & 63;
    const int r   = l & 15;        // batch row within the block's 16-row group
    const int q   = l >> 4;        // quad 0..3
    const int row0 = blockIdx.x * 16;

    // exchange buffers: [layer][mt][lane] -> 4 KB
    __shared__ uint2 xbuf[2][4][64];

    // pin this wave's weight fragments (compile-time register indices;
    // only the ADDRESS depends on wv)
    const f16x4* wf = (const f16x4*)wfrags;
    f16x4 w0f[4], w1xf[4], w1hf[4];
#pragma unroll
    for (int kf = 0; kf < 4; ++kf) {
        w0f[kf]  = wf[(wv * 4 + kf) * 64 + l];            // Wh0, mt=wv
        w1xf[kf] = wf[(16 + wv * 8 + kf) * 64 + l];       // Wx1, mt=wv
        w1hf[kf] = wf[(16 + wv * 8 + 4 + kf) * 64 + l];   // Wh1, mt=wv
    }

    // b1 folded into layer-1 C init: wave's units are wv*16 + q*4 + i
    const f32x4 b1v = ((const f32x4*)b1)[wv * 4 + q];

    // full hidden state as B-fragments (read back from LDS each layer)
    f16x4 h0f[4], h1f[4];
#pragma unroll
    for (int kf = 0; kf < 4; ++kf)
#pragma unroll
        for (int j = 0; j < 4; ++j) {
            h0f[kf][j] = (_Float16)0.0f;
            h1f[kf][j] = (_Float16)0.0f;
        }

    const f32x4* embWv = (const f32x4*)embW;
    const int tokbase = (row0 + r) * SEQ;

    // prefetch t=0 token + embW C-init (1 tile per wave)
    int tok = tokens[tokbase];
    f32x4 e = embWv[tok * 16 + wv * 4 + q];

    for (int t = 0; t < SEQ; ++t) {
        // next token load issued early (consumed mid-iteration)
        int t1c = (t + 1 < SEQ) ? (t + 1) : t;
        int tokn = tokens[tokbase + t1c];

        // ---- front: layer-0 chain interleaved with Wh1*h1(t-1) chain ----
        f32x4 acc = e;                     // embW C-init (b0 folded)
        f32x4 bb; bb[0] = 0.f; bb[1] = 0.f; bb[2] = 0.f; bb[3] = 0.f;
#pragma unroll
        for (int kf = 0; kf < 4; ++kf) {   // 8 MFMAs, two independent chains
            acc = __builtin_amdgcn_mfma_f32_16x16x16f16(
                w0f[kf], h0f[kf], acc, 0, 0, 0);
            bb = __builtin_amdgcn_mfma_f32_16x16x16f16(
                w1hf[kf], h1f[kf], bb, 0, 0, 0);
        }
        f16x4 nh0 = tanh_pack(acc);
        xbuf[0][wv][l] = *(const uint2*)&nh0;
        lds_barrier();
#pragma unroll
        for (int kf = 0; kf < 4; ++kf) {   // compile-time reg dests
            uint2 u = xbuf[0][kf][l];
            h0f[kf] = *(const f16x4*)&u;
        }

        // prefetch embW for next step (stays in flight across barriers)
        e = embWv[tokn * 16 + wv * 4 + q];

        // ---- back: a = b1 + Wh1*h1 + Wx1*h0n (4-deep chain) ----
        f32x4 a = bb + b1v;
#pragma unroll
        for (int kf = 0; kf < 4; ++kf)
            a = __builtin_amdgcn_mfma_f32_16x16x16f16(
                w1xf[kf], h0f[kf], a, 0, 0, 0);

        f16x4 nh1 = tanh_pack(a);
        xbuf[1][wv][l] = *(const uint2*)&nh1;
        lds_barrier();
#pragma unroll
        for (int kf = 0; kf < 4; ++kf) {
            uint2 u = xbuf[1][kf][l];
            h1f[kf] = *(const f16x4*)&u;
        }
    }

    // ---- output head: out[row] = sigmoid(h1 . Wout + bout) ----
    // every wave holds the full h1 after the final LDS read; wave 0 stores.
    if (wv == 0) {
        float accv = 0.0f;
#pragma unroll
        for (int kf = 0; kf < 4; ++kf) {
            f32x4 wo = ((const f32x4*)Wout)[kf * 4 + q];
#pragma unroll
            for (int j = 0; j < 4; ++j)
                accv = fmaf((float)h1f[kf][j], wo[j], accv);
        }
        accv += __shfl_down(accv, 16);
        accv += __shfl_down(accv, 32);
        if (l < 16) {
            float z = accv + bout[0];
            out[row0 + r] = 1.0f / (1.0f + __expf(-z));
        }
    }
}

extern "C" void kernel_launch(void* const* d_in, const int* in_sizes, int n_in,
                              void* d_out, int out_size, void* d_ws, size_t ws_size,
                              hipStream_t stream) {
    const int*   tokens = (const int*)d_in[0];
    const float* emb    = (const float*)d_in[1];
    const float* Wx0    = (const float*)d_in[2];
    const float* Wh0    = (const float*)d_in[3];
    const float* b0     = (const float*)d_in[4];
    const float* Wx1    = (const float*)d_in[5];
    const float* Wh1    = (const float*)d_in[6];
    const float* b1     = (const float*)d_in[7];
    const float* Wout   = (const float*)d_in[8];
    const float* bout   = (const float*)d_in[9];
    float* out = (float*)d_out;

    // ws layout: embW fp32 (2,560,000 B) | packed f16 weight frags (24,576 B)
    float* embW = (float*)d_ws;
    _Float16* wfrags =
        (_Float16*)((char*)d_ws + (size_t)TOTAL_WORDS * UNITS * 4);

    prep_kernel<<<2548, 256, 0, stream>>>(emb, Wx0, b0, Wh0, Wx1, Wh1,
                                          embW, wfrags);
    rnn_mfma_kernel<<<BATCH / 16, 256, 0, stream>>>(tokens, embW, wfrags,
                                                    b1, Wout, bout, out);
}

// Round 8
// 139.250 us; speedup vs baseline: 1.1873x; 1.1873x over previous
//
#include <hip/hip_runtime.h>

// Problem constants (from reference)
#define TOTAL_WORDS 10000
#define EMB 100
#define SEQ 80
#define UNITS 64
#define BATCH 16384

// ---------------------------------------------------------------------------
// Register-resident 2-layer SimpleRNN on v_mfma_f32_16x16x16f16, 4-wave
// M-split, deep-pipelined gathers.
//
//  R7 lesson: at 4 waves/SIMD the wall was NOT issue -- it was (a) the
//  serialized token->embW global-latency chain with only 1 step of slack
//  (tokens 5MB + embW 2.5MB > 4MB XCD L2 -> ~450-900 cyc each), and (b) the
//  CU-shared DS pipe at ~50% busy. This round:
//   - tokens prefetched 8 steps ahead (int4 A/B register window; step loop
//     unrolled x4 so every element access is compile-time -- R5 scratch rule)
//   - embW rows prefetched 2 steps ahead (3-stage e0/e1/e2 pipeline)
//   - tanh computed in packed f16 (v_pk_fma_f16): ~12 VALU / 8 values
//  Everything else (M-split, D-layout==B-layout K=16 exchange, LDS-only
//  barrier that leaves global prefetches in flight) carried from R7.
// ---------------------------------------------------------------------------

typedef _Float16 f16x4 __attribute__((ext_vector_type(4)));
typedef _Float16 h2    __attribute__((ext_vector_type(2)));
typedef __fp16   fp16x2r __attribute__((ext_vector_type(2)));  // cvt_pkrtz ret
typedef float    f32x4 __attribute__((ext_vector_type(4)));

__device__ __forceinline__ h2 pkcvt(float a, float b) {
    fp16x2r t = __builtin_amdgcn_cvt_pkrtz(a, b);
    h2 o; o[0] = (_Float16)t[0]; o[1] = (_Float16)t[1];
    return o;
}

__device__ __forceinline__ h2 tanh_h2(h2 x) {
    // odd deg-5 in packed f16: |x| <= ~0.3 -> added err ~2e-4 (f16 rounding)
    const _Float16 c3 = (_Float16)(-0.33333333f);
    const _Float16 c5 = (_Float16)(0.13333333f);
    h2 x2 = x * x;
    h2 p  = x2 * c5 + c3;     // v_pk_fma_f16
    h2 x3 = x2 * x;
    return x3 * p + x;        // v_pk_fma_f16
}

__device__ __forceinline__ f16x4 tanh_pack(f32x4 a) {
    h2 lo = tanh_h2(pkcvt(a[0], a[1]));
    h2 hi = tanh_h2(pkcvt(a[2], a[3]));
    f16x4 o;
    o[0] = lo[0]; o[1] = lo[1]; o[2] = hi[0]; o[3] = hi[1];
    return o;
}

// LDS-only barrier: drains ds ops, leaves global loads in flight.
__device__ __forceinline__ void lds_barrier() {
    asm volatile("s_waitcnt lgkmcnt(0)\n\ts_barrier" ::: "memory");
}

// ------------------- fused prologue: embW + weight packing -----------------
// blocks [0,2500): embW rows (4 per block), Wx0 staged in LDS.
// blocks [2500,2548): pack 48 A-frags (16 layer0 + 32 layer1), 256 f16 each.
// A-frag(mt,kf) element (lane l, j) = W[kf*16 + (l>>4)*4 + j][mt*16 + (l&15)]
__global__ void prep_kernel(const float* __restrict__ emb,
                            const float* __restrict__ Wx0,
                            const float* __restrict__ b0,
                            const float* __restrict__ Wh0,
                            const float* __restrict__ Wx1,
                            const float* __restrict__ Wh1,
                            float* __restrict__ embW,
                            _Float16* __restrict__ wfrags) {
    int b = blockIdx.x;
    if (b < 2500) {
        __shared__ float wx[EMB * UNITS];  // 25.6 KB
        for (int i = threadIdx.x; i < EMB * UNITS; i += 256)
            wx[i] = Wx0[i];
        __syncthreads();
        int v = b * 4 + (threadIdx.x >> 6);   // wave-uniform -> s_load for emb
        int u = threadIdx.x & 63;
        float acc = b0[u];
#pragma unroll 10
        for (int k = 0; k < EMB; ++k)
            acc = fmaf(emb[v * EMB + k], wx[k * UNITS + u], acc);
        embW[v * UNITS + u] = acc;
    } else {
        int e = (b - 2500) * 256 + threadIdx.x;  // 0..12287
        int f = e >> 8;                          // frag id 0..47
        int rr = e & 255;
        int l = rr >> 2, j = rr & 3;
        int m = l & 15, q = l >> 4;
        int kloc = q * 4 + j;
        float v;
        if (f < 16) {                            // layer0: Wh0
            int mt = f >> 2, kf = f & 3;
            int k = kf * 16 + kloc;
            v = Wh0[k * UNITS + mt * 16 + m];
        } else {                                 // layer1: [Wx1;Wh1], K=128
            int f2 = f - 16;
            int mt = f2 >> 3, kf = f2 & 7;       // kf<4: Wx1, kf>=4: Wh1
            int k = kf * 16 + kloc;
            v = (k < 64) ? Wx1[k * UNITS + mt * 16 + m]
                         : Wh1[(k - 64) * UNITS + mt * 16 + m];
        }
        wfrags[e] = (_Float16)v;
    }
}

// ------------------------------ main kernel --------------------------------
// One RNN timestep; TOK2 = token for t+2 (compile-time selected register).
#define RNN_STEP(TOK2)                                                        \
    {                                                                         \
        f32x4 e2 = embWv[(TOK2) * 16 + wv * 4 + q];  /* prefetch t+2 */       \
        f32x4 acc = e0;                                                       \
        f32x4 bb; bb[0] = 0.f; bb[1] = 0.f; bb[2] = 0.f; bb[3] = 0.f;         \
        _Pragma("unroll")                                                     \
        for (int kf = 0; kf < 4; ++kf) {                                      \
            acc = __builtin_amdgcn_mfma_f32_16x16x16f16(                      \
                w0f[kf], h0f[kf], acc, 0, 0, 0);                              \
            bb = __builtin_amdgcn_mfma_f32_16x16x16f16(                       \
                w1hf[kf], h1f[kf], bb, 0, 0, 0);                              \
        }                                                                     \
        f16x4 nh0 = tanh_pack(acc);                                           \
        xbuf[0][wv][l] = *(const uint2*)&nh0;                                 \
        lds_barrier();                                                        \
        _Pragma("unroll")                                                     \
        for (int kf = 0; kf < 4; ++kf) {                                      \
            uint2 u_ = xbuf[0][kf][l];                                        \
            h0f[kf] = *(const f16x4*)&u_;                                     \
        }                                                                     \
        f32x4 a = bb + b1v;                                                   \
        _Pragma("unroll")                                                     \
        for (int kf = 0; kf < 4; ++kf)                                        \
            a = __builtin_amdgcn_mfma_f32_16x16x16f16(                        \
                w1xf[kf], h0f[kf], a, 0, 0, 0);                               \
        f16x4 nh1 = tanh_pack(a);                                             \
        xbuf[1][wv][l] = *(const uint2*)&nh1;                                 \
        lds_barrier();                                                        \
        _Pragma("unroll")                                                     \
        for (int kf = 0; kf < 4; ++kf) {                                      \
            uint2 u_ = xbuf[1][kf][l];                                        \
            h1f[kf] = *(const f16x4*)&u_;                                     \
        }                                                                     \
        e0 = e1; e1 = e2;                                                     \
    }

__global__ __launch_bounds__(256, 4) void rnn_mfma_kernel(
    const int*      __restrict__ tokens,   // [BATCH][SEQ]
    const float*    __restrict__ embW,     // [TOTAL_WORDS][UNITS]
    const _Float16* __restrict__ wfrags,   // packed f16 A-frags
    const float*    __restrict__ b1,       // [UNITS]
    const float*    __restrict__ Wout,     // [UNITS]
    const float*    __restrict__ bout,     // [1]
    float*          __restrict__ out) {    // [BATCH]
    const int tid = threadIdx.x;
    const int wv  = tid >> 6;      // wave 0..3: owns output tile mt = wv
    const int l   = tid & 63;
    const int r   = l & 15;        // batch row within the block's 16-row group
    const int q   = l >> 4;        // quad 0..3
    const int row0 = blockIdx.x * 16;

    // exchange buffers: [layer][mt][lane] -> 4 KB
    __shared__ uint2 xbuf[2][4][64];

    // pin this wave's weight fragments (compile-time register indices;
    // only the ADDRESS depends on wv)
    const f16x4* wf = (const f16x4*)wfrags;
    f16x4 w0f[4], w1xf[4], w1hf[4];
#pragma unroll
    for (int kf = 0; kf < 4; ++kf) {
        w0f[kf]  = wf[(wv * 4 + kf) * 64 + l];            // Wh0, mt=wv
        w1xf[kf] = wf[(16 + wv * 8 + kf) * 64 + l];       // Wx1, mt=wv
        w1hf[kf] = wf[(16 + wv * 8 + 4 + kf) * 64 + l];   // Wh1, mt=wv
    }

    // b1 folded into layer-1 C init: wave's units are wv*16 + q*4 + i
    const f32x4 b1v = ((const f32x4*)b1)[wv * 4 + q];

    // full hidden state as B-fragments (read back from LDS each layer)
    f16x4 h0f[4], h1f[4];
#pragma unroll
    for (int kf = 0; kf < 4; ++kf)
#pragma unroll
        for (int j = 0; j < 4; ++j) {
            h0f[kf][j] = (_Float16)0.0f;
            h1f[kf][j] = (_Float16)0.0f;
        }

    const f32x4* embWv = (const f32x4*)embW;
    const int tokbase = (row0 + r) * SEQ;

    // token window: A = tokens[t0..t0+3], B = tokens[t0+4..t0+7] (t0 = 4k)
    int4 tkA = *(const int4*)&tokens[tokbase];
    int4 tkB = *(const int4*)&tokens[tokbase + 4];
    // embW pipeline: e0 for t, e1 for t+1 (e2 for t+2 issued inside the step)
    f32x4 e0 = embWv[tkA.x * 16 + wv * 4 + q];
    f32x4 e1 = embWv[tkA.y * 16 + wv * 4 + q];

    for (int k = 0; k < SEQ / 4; ++k) {
        // token prefetch 8 steps ahead (clamped tail reads stay in-bounds
        // and only feed dead e-prefetches)
        int off = (4 * k + 8 <= SEQ - 4) ? (4 * k + 8) : (SEQ - 4);
        int4 tkC = *(const int4*)&tokens[tokbase + off];

        RNN_STEP(tkA.z)   // t = 4k   : t+2 = 4k+2
        RNN_STEP(tkA.w)   // t = 4k+1 : t+2 = 4k+3
        RNN_STEP(tkB.x)   // t = 4k+2 : t+2 = 4k+4
        RNN_STEP(tkB.y)   // t = 4k+3 : t+2 = 4k+5

        tkA = tkB; tkB = tkC;
    }

    // ---- output head: out[row] = sigmoid(h1 . Wout + bout) ----
    // every wave holds the full h1 after the final LDS read; wave 0 stores.
    if (wv == 0) {
        float accv = 0.0f;
#pragma unroll
        for (int kf = 0; kf < 4; ++kf) {
            f32x4 wo = ((const f32x4*)Wout)[kf * 4 + q];
#pragma unroll
            for (int j = 0; j < 4; ++j)
                accv = fmaf((float)h1f[kf][j], wo[j], accv);
        }
        accv += __shfl_down(accv, 16);
        accv += __shfl_down(accv, 32);
        if (l < 16) {
            float z = accv + bout[0];
            out[row0 + r] = 1.0f / (1.0f + __expf(-z));
        }
    }
}

extern "C" void kernel_launch(void* const* d_in, const int* in_sizes, int n_in,
                              void* d_out, int out_size, void* d_ws, size_t ws_size,
                              hipStream_t stream) {
    const int*   tokens = (const int*)d_in[0];
    const float* emb    = (const float*)d_in[1];
    const float* Wx0    = (const float*)d_in[2];
    const float* Wh0    = (const float*)d_in[3];
    const float* b0     = (const float*)d_in[4];
    const float* Wx1    = (const float*)d_in[5];
    const float* Wh1    = (const float*)d_in[6];
    const float* b1     = (const float*)d_in[7];
    const float* Wout   = (const float*)d_in[8];
    const float* bout   = (const float*)d_in[9];
    float* out = (float*)d_out;

    // ws layout: embW fp32 (2,560,000 B) | packed f16 weight frags (24,576 B)
    float* embW = (float*)d_ws;
    _Float16* wfrags =
        (_Float16*)((char*)d_ws + (size_t)TOTAL_WORDS * UNITS * 4);

    prep_kernel<<<2548, 256, 0, stream>>>(emb, Wx0, b0, Wh0, Wx1, Wh1,
                                          embW, wfrags);
    rnn_mfma_kernel<<<BATCH / 16, 256, 0, stream>>>(tokens, embW, wfrags,
                                                    b1, Wout, bout, out);
}

// Round 9
// 137.189 us; speedup vs baseline: 1.2051x; 1.0150x over previous
//
#include <hip/hip_runtime.h>

// Problem constants (from reference)
#define TOTAL_WORDS 10000
#define EMB 100
#define SEQ 80
#define UNITS 64
#define BATCH 16384

// ---------------------------------------------------------------------------
// Register-resident 2-layer SimpleRNN on v_mfma_f32_16x16x16f16.
// R9: pair-split for DS-pipe relief (R8 post-mortem: DS pipe ~71% of wall).
//
//  - Block = 4 waves = 2 independent PAIRS; pair g owns batch rows
//    [blockIdx*32 + g*16, +16). Within a pair, wave half p owns output unit
//    tiles {2p, 2p+1} for both layers -> each wave carries 2x R8's work.
//  - Exchange: wave writes its two tanh'd D-frags as ONE ds_write_b128
//    (lane-contiguous 16B = canonical conflict-free), reads both halves as
//    2 ds_read_b128 per layer: 6 DS instr/wave-step vs R8's 10, at half the
//    waves -> per-CU DS demand ~2.2x lower.
//  - D-layout == B-layout (16x16x16 f16): write format = read format, no
//    transpose. All register arrays use compile-time indices (R5 lesson).
//  - MFMA: 24/wave-step in 4 independent 4-deep chains (high ILP to cover
//    2 waves/SIMD occupancy).
//  - Deep pipeline carried from R8: tokens 8 steps ahead (int4 window, x4
//    unrolled step loop), embW rows 2 steps ahead. lds_barrier() =
//    `s_waitcnt lgkmcnt(0); s_barrier` keeps global prefetches in flight.
//  - Barrier safety without parity buffers: lgkmcnt(0) before s_barrier
//    means every wave's reads of slot X completed before it can reach the
//    next write of slot X.
// ---------------------------------------------------------------------------

typedef _Float16 f16x4 __attribute__((ext_vector_type(4)));
typedef _Float16 h2    __attribute__((ext_vector_type(2)));
typedef __fp16   fp16x2r __attribute__((ext_vector_type(2)));  // cvt_pkrtz ret
typedef float    f32x4 __attribute__((ext_vector_type(4)));

__device__ __forceinline__ h2 pkcvt(float a, float b) {
    fp16x2r t = __builtin_amdgcn_cvt_pkrtz(a, b);
    h2 o; o[0] = (_Float16)t[0]; o[1] = (_Float16)t[1];
    return o;
}

__device__ __forceinline__ h2 tanh_h2(h2 x) {
    // odd deg-5 in packed f16: |x| <= ~0.3 -> added err ~2e-4 (f16 rounding)
    const _Float16 c3 = (_Float16)(-0.33333333f);
    const _Float16 c5 = (_Float16)(0.13333333f);
    h2 x2 = x * x;
    h2 p  = x2 * c5 + c3;     // v_pk_fma_f16
    h2 x3 = x2 * x;
    return x3 * p + x;        // v_pk_fma_f16
}

__device__ __forceinline__ f16x4 tanh_pack(f32x4 a) {
    h2 lo = tanh_h2(pkcvt(a[0], a[1]));
    h2 hi = tanh_h2(pkcvt(a[2], a[3]));
    f16x4 o;
    o[0] = lo[0]; o[1] = lo[1]; o[2] = hi[0]; o[3] = hi[1];
    return o;
}

// LDS-only barrier: drains ds ops, leaves global loads in flight.
__device__ __forceinline__ void lds_barrier() {
    asm volatile("s_waitcnt lgkmcnt(0)\n\ts_barrier" ::: "memory");
}

// ------------------- fused prologue: embW + weight packing -----------------
// blocks [0,2500): embW rows (4 per block), Wx0 staged in LDS.
// blocks [2500,2548): pack 48 A-frags (16 layer0 + 32 layer1), 256 f16 each.
// A-frag(mt,kf) element (lane l, j) = W[kf*16 + (l>>4)*4 + j][mt*16 + (l&15)]
__global__ void prep_kernel(const float* __restrict__ emb,
                            const float* __restrict__ Wx0,
                            const float* __restrict__ b0,
                            const float* __restrict__ Wh0,
                            const float* __restrict__ Wx1,
                            const float* __restrict__ Wh1,
                            float* __restrict__ embW,
                            _Float16* __restrict__ wfrags) {
    int b = blockIdx.x;
    if (b < 2500) {
        __shared__ float wx[EMB * UNITS];  // 25.6 KB
        for (int i = threadIdx.x; i < EMB * UNITS; i += 256)
            wx[i] = Wx0[i];
        __syncthreads();
        int v = b * 4 + (threadIdx.x >> 6);
        int u = threadIdx.x & 63;
        float acc = b0[u];
#pragma unroll 10
        for (int k = 0; k < EMB; ++k)
            acc = fmaf(emb[v * EMB + k], wx[k * UNITS + u], acc);
        embW[v * UNITS + u] = acc;
    } else {
        int e = (b - 2500) * 256 + threadIdx.x;  // 0..12287
        int f = e >> 8;                          // frag id 0..47
        int rr = e & 255;
        int l = rr >> 2, j = rr & 3;
        int m = l & 15, q = l >> 4;
        int kloc = q * 4 + j;
        float v;
        if (f < 16) {                            // layer0: Wh0
            int mt = f >> 2, kf = f & 3;
            int k = kf * 16 + kloc;
            v = Wh0[k * UNITS + mt * 16 + m];
        } else {                                 // layer1: [Wx1;Wh1], K=128
            int f2 = f - 16;
            int mt = f2 >> 3, kf = f2 & 7;       // kf<4: Wx1, kf>=4: Wh1
            int k = kf * 16 + kloc;
            v = (k < 64) ? Wx1[k * UNITS + mt * 16 + m]
                         : Wh1[(k - 64) * UNITS + mt * 16 + m];
        }
        wfrags[e] = (_Float16)v;
    }
}

// ------------------------------ main kernel --------------------------------
// One RNN timestep; TOK2 = token for t+2 (compile-time selected register).
#define RNN_STEP(TOK2)                                                        \
    {                                                                         \
        f32x4 e2a = embWv[(TOK2) * 16 + (2 * p) * 4 + q];     /* t+2 */       \
        f32x4 e2b = embWv[(TOK2) * 16 + (2 * p + 1) * 4 + q];                 \
        f32x4 acc0 = e0a, acc1 = e0b;                                         \
        f32x4 bb0, bb1;                                                       \
        bb0[0]=0.f; bb0[1]=0.f; bb0[2]=0.f; bb0[3]=0.f;                       \
        bb1[0]=0.f; bb1[1]=0.f; bb1[2]=0.f; bb1[3]=0.f;                       \
        _Pragma("unroll")                                                     \
        for (int kf = 0; kf < 4; ++kf) {  /* 4 independent 4-deep chains */   \
            acc0 = __builtin_amdgcn_mfma_f32_16x16x16f16(                     \
                w0f[0][kf], h0f[kf], acc0, 0, 0, 0);                          \
            acc1 = __builtin_amdgcn_mfma_f32_16x16x16f16(                     \
                w0f[1][kf], h0f[kf], acc1, 0, 0, 0);                          \
            bb0 = __builtin_amdgcn_mfma_f32_16x16x16f16(                      \
                w1hf[0][kf], h1f[kf], bb0, 0, 0, 0);                          \
            bb1 = __builtin_amdgcn_mfma_f32_16x16x16f16(                      \
                w1hf[1][kf], h1f[kf], bb1, 0, 0, 0);                          \
        }                                                                     \
        {                                                                     \
            f16x4 na = tanh_pack(acc0), nb = tanh_pack(acc1);                 \
            uint2 ua = *(const uint2*)&na, ub = *(const uint2*)&nb;           \
            uint4 pk; pk.x = ua.x; pk.y = ua.y; pk.z = ub.x; pk.w = ub.y;     \
            xbuf[0][g][p][l] = pk;                                            \
        }                                                                     \
        lds_barrier();                                                        \
        {                                                                     \
            uint4 h0 = xbuf[0][g][0][l];                                      \
            uint4 h1_ = xbuf[0][g][1][l];                                     \
            h0f[0] = *(const f16x4*)&h0.x;  /* elems x,y = frag 0 */          \
            h0f[1] = *(const f16x4*)&h0.z;                                    \
            h0f[2] = *(const f16x4*)&h1_.x;                                   \
            h0f[3] = *(const f16x4*)&h1_.z;                                   \
        }                                                                     \
        f32x4 a0 = bb0 + b1v0, a1 = bb1 + b1v1;                               \
        _Pragma("unroll")                                                     \
        for (int kf = 0; kf < 4; ++kf) {  /* 2 independent 4-deep chains */   \
            a0 = __builtin_amdgcn_mfma_f32_16x16x16f16(                       \
                w1xf[0][kf], h0f[kf], a0, 0, 0, 0);                           \
            a1 = __builtin_amdgcn_mfma_f32_16x16x16f16(                       \
                w1xf[1][kf], h0f[kf], a1, 0, 0, 0);                           \
        }                                                                     \
        {                                                                     \
            f16x4 na = tanh_pack(a0), nb = tanh_pack(a1);                     \
            uint2 ua = *(const uint2*)&na, ub = *(const uint2*)&nb;           \
            uint4 pk; pk.x = ua.x; pk.y = ua.y; pk.z = ub.x; pk.w = ub.y;     \
            xbuf[1][g][p][l] = pk;                                            \
        }                                                                     \
        lds_barrier();                                                        \
        {                                                                     \
            uint4 h0 = xbuf[1][g][0][l];                                      \
            uint4 h1_ = xbuf[1][g][1][l];                                     \
            h1f[0] = *(const f16x4*)&h0.x;                                    \
            h1f[1] = *(const f16x4*)&h0.z;                                    \
            h1f[2] = *(const f16x4*)&h1_.x;                                   \
            h1f[3] = *(const f16x4*)&h1_.z;                                   \
        }                                                                     \
        e0a = e1a; e0b = e1b; e1a = e2a; e1b = e2b;                           \
    }

__global__ __launch_bounds__(256, 2) void rnn_mfma_kernel(
    const int*      __restrict__ tokens,   // [BATCH][SEQ]
    const float*    __restrict__ embW,     // [TOTAL_WORDS][UNITS]
    const _Float16* __restrict__ wfrags,   // packed f16 A-frags
    const float*    __restrict__ b1,       // [UNITS]
    const float*    __restrict__ Wout,     // [UNITS]
    const float*    __restrict__ bout,     // [1]
    float*          __restrict__ out) {    // [BATCH]
    const int tid = threadIdx.x;
    const int wv  = tid >> 6;      // wave 0..3
    const int g   = wv >> 1;       // pair (row group) 0/1
    const int p   = wv & 1;        // half within pair: owns tiles {2p, 2p+1}
    const int l   = tid & 63;
    const int r   = l & 15;        // batch row within the pair's 16-row group
    const int q   = l >> 4;        // quad 0..3
    const int row0 = blockIdx.x * 32 + g * 16;

    // exchange buffers: [layer][group][half][lane] -> 8 KB
    __shared__ uint4 xbuf[2][2][2][64];

    // pin this wave's weight fragments for tiles {2p, 2p+1} (48 VGPRs);
    // compile-time register indices, only ADDRESSES depend on p.
    const f16x4* wf = (const f16x4*)wfrags;
    f16x4 w0f[2][4], w1xf[2][4], w1hf[2][4];
#pragma unroll
    for (int j = 0; j < 2; ++j)
#pragma unroll
        for (int kf = 0; kf < 4; ++kf) {
            int mt = 2 * p + j;
            w0f[j][kf]  = wf[(mt * 4 + kf) * 64 + l];            // Wh0
            w1xf[j][kf] = wf[(16 + mt * 8 + kf) * 64 + l];       // Wx1
            w1hf[j][kf] = wf[(16 + mt * 8 + 4 + kf) * 64 + l];   // Wh1
        }

    // b1 folded into layer-1 C init
    const f32x4 b1v0 = ((const f32x4*)b1)[(2 * p) * 4 + q];
    const f32x4 b1v1 = ((const f32x4*)b1)[(2 * p + 1) * 4 + q];

    // full hidden state as B-fragments (round-trips through LDS)
    f16x4 h0f[4], h1f[4];
#pragma unroll
    for (int kf = 0; kf < 4; ++kf)
#pragma unroll
        for (int j = 0; j < 4; ++j) {
            h0f[kf][j] = (_Float16)0.0f;
            h1f[kf][j] = (_Float16)0.0f;
        }

    const f32x4* embWv = (const f32x4*)embW;
    const int tokbase = (row0 + r) * SEQ;

    // token window: A = tokens[t0..t0+3], B = tokens[t0+4..t0+7]
    int4 tkA = *(const int4*)&tokens[tokbase];
    int4 tkB = *(const int4*)&tokens[tokbase + 4];
    // embW pipeline: (e0a,e0b) for t, (e1a,e1b) for t+1
    f32x4 e0a = embWv[tkA.x * 16 + (2 * p) * 4 + q];
    f32x4 e0b = embWv[tkA.x * 16 + (2 * p + 1) * 4 + q];
    f32x4 e1a = embWv[tkA.y * 16 + (2 * p) * 4 + q];
    f32x4 e1b = embWv[tkA.y * 16 + (2 * p + 1) * 4 + q];

    for (int k = 0; k < SEQ / 4; ++k) {
        // token prefetch 8 steps ahead (clamped tail reads stay in-bounds
        // and only feed dead e-prefetches)
        int off = (4 * k + 8 <= SEQ - 4) ? (4 * k + 8) : (SEQ - 4);
        int4 tkC = *(const int4*)&tokens[tokbase + off];

        RNN_STEP(tkA.z)   // t = 4k   : t+2 = 4k+2
        RNN_STEP(tkA.w)   // t = 4k+1 : t+2 = 4k+3
        RNN_STEP(tkB.x)   // t = 4k+2 : t+2 = 4k+4
        RNN_STEP(tkB.y)   // t = 4k+3 : t+2 = 4k+5

        tkA = tkB; tkB = tkC;
    }

    // ---- output head: out[row] = sigmoid(h1 . Wout + bout) ----
    // both waves of a pair hold the full h1; half p==0 stores its group.
    if (p == 0) {
        float accv = 0.0f;
#pragma unroll
        for (int kf = 0; kf < 4; ++kf) {
            f32x4 wo = ((const f32x4*)Wout)[kf * 4 + q];
#pragma unroll
            for (int j = 0; j < 4; ++j)
                accv = fmaf((float)h1f[kf][j], wo[j], accv);
        }
        accv += __shfl_down(accv, 16);
        accv += __shfl_down(accv, 32);
        if (l < 16) {
            float z = accv + bout[0];
            out[row0 + r] = 1.0f / (1.0f + __expf(-z));
        }
    }
}

extern "C" void kernel_launch(void* const* d_in, const int* in_sizes, int n_in,
                              void* d_out, int out_size, void* d_ws, size_t ws_size,
                              hipStream_t stream) {
    const int*   tokens = (const int*)d_in[0];
    const float* emb    = (const float*)d_in[1];
    const float* Wx0    = (const float*)d_in[2];
    const float* Wh0    = (const float*)d_in[3];
    const float* b0     = (const float*)d_in[4];
    const float* Wx1    = (const float*)d_in[5];
    const float* Wh1    = (const float*)d_in[6];
    const float* b1     = (const float*)d_in[7];
    const float* Wout   = (const float*)d_in[8];
    const float* bout   = (const float*)d_in[9];
    float* out = (float*)d_out;

    // ws layout: embW fp32 (2,560,000 B) | packed f16 weight frags (24,576 B)
    float* embW = (float*)d_ws;
    _Float16* wfrags =
        (_Float16*)((char*)d_ws + (size_t)TOTAL_WORDS * UNITS * 4);

    prep_kernel<<<2548, 256, 0, stream>>>(emb, Wx0, b0, Wh0, Wx1, Wh1,
                                          embW, wfrags);
    rnn_mfma_kernel<<<BATCH / 32, 256, 0, stream>>>(tokens, embW, wfrags,
                                                    b1, Wout, bout, out);
}

// Round 10
// 136.387 us; speedup vs baseline: 1.2122x; 1.0059x over previous
//
#include <hip/hip_runtime.h>

// Problem constants (from reference)
#define TOTAL_WORDS 10000
#define EMB 100
#define SEQ 80
#define UNITS 64
#define BATCH 16384

// ---------------------------------------------------------------------------
// R10: producer-consumer LAYER pipeline (R9 falsified the DS-pipe theory;
// the wall is the per-wave barrier-serialized critical path).
//
//  - Block = 2 waves, 16 batch rows. Wave A runs the ENTIRE layer-0
//    recurrence (h0 self-contained, in registers via the D==B K=16 layout
//    identity; no LDS reads, never waits on B) and ships h0n(t) into a
//    depth-2 LDS FIFO. Wave B runs one step behind: consumes h0n(t) (already
//    resident since the previous barrier), h1 recurrence in registers.
//  - ONE lds_barrier per step (was 2), and it no longer cuts a dependent
//    chain: A's and B's serial chains run concurrently.
//  - B reads h0n from LDS in K=32 B-frag layout -> mfma_f32_16x16x32_f16
//    for Wx1*h0n (8 MFMAs vs 16). Row stride 72 f16 = 144 B: 16B-aligned
//    b128, and bank-uniform (8 dwords/bank = minimum) -> conflict-free.
//  - FIFO safety: A writes slot t%2, B reads slot (t-1)%2 (disjoint);
//    lgkmcnt(0) before each s_barrier drains A's writes and B's reads.
//    Both waves execute exactly SEQ barriers; the epilogue (B's step 79 +
//    head) has none, so no barrier-after-exit hazard.
//  - All register arrays compile-time indexed (R5 scratch lesson). Token
//    window 8 ahead + embW 2 ahead pipeline carried from R8 (wave A only).
// ---------------------------------------------------------------------------

typedef _Float16 f16x4 __attribute__((ext_vector_type(4)));
typedef _Float16 f16x8 __attribute__((ext_vector_type(8)));
typedef _Float16 h2    __attribute__((ext_vector_type(2)));
typedef __fp16   fp16x2r __attribute__((ext_vector_type(2)));  // cvt_pkrtz ret
typedef float    f32x4 __attribute__((ext_vector_type(4)));

__device__ __forceinline__ h2 pkcvt(float a, float b) {
    fp16x2r t = __builtin_amdgcn_cvt_pkrtz(a, b);
    h2 o; o[0] = (_Float16)t[0]; o[1] = (_Float16)t[1];
    return o;
}

__device__ __forceinline__ h2 tanh_h2(h2 x) {
    // odd deg-5 in packed f16: |x| <= ~0.3 -> added err ~2e-4
    const _Float16 c3 = (_Float16)(-0.33333333f);
    const _Float16 c5 = (_Float16)(0.13333333f);
    h2 x2 = x * x;
    h2 p  = x2 * c5 + c3;     // v_pk_fma_f16
    h2 x3 = x2 * x;
    return x3 * p + x;        // v_pk_fma_f16
}

__device__ __forceinline__ f16x4 tanh_pack(f32x4 a) {
    h2 lo = tanh_h2(pkcvt(a[0], a[1]));
    h2 hi = tanh_h2(pkcvt(a[2], a[3]));
    f16x4 o;
    o[0] = lo[0]; o[1] = lo[1]; o[2] = hi[0]; o[3] = hi[1];
    return o;
}

// LDS-only barrier: drains ds ops, leaves global loads in flight.
__device__ __forceinline__ void lds_barrier() {
    asm volatile("s_waitcnt lgkmcnt(0)\n\ts_barrier" ::: "memory");
}

// ------------------- fused prologue: embW + weight packing -----------------
// blocks [0,2500): embW rows (4 per block), Wx0 staged in LDS.
// blocks [2500,2548): pack weight frags, 12288 f16 total:
//   [0,4096):    Wh0 K=16 frags f=mt*4+kf: elem(l,j<4) =
//                Wh0[kf*16+(l>>4)*4+j][mt*16+(l&15)]
//   [4096,8192): Wh1 K=16 frags, same mapping on Wh1
//   [8192,12288):Wx1 K=32 frags f=mt*2+kf (512 f16 each): elem(l,j<8) =
//                Wx1[kf*32+(l>>4)*8+j][mt*16+(l&15)]
__global__ void prep_kernel(const float* __restrict__ emb,
                            const float* __restrict__ Wx0,
                            const float* __restrict__ b0,
                            const float* __restrict__ Wh0,
                            const float* __restrict__ Wx1,
                            const float* __restrict__ Wh1,
                            float* __restrict__ embW,
                            _Float16* __restrict__ wfrags) {
    int b = blockIdx.x;
    if (b < 2500) {
        __shared__ float wx[EMB * UNITS];  // 25.6 KB
        for (int i = threadIdx.x; i < EMB * UNITS; i += 256)
            wx[i] = Wx0[i];
        __syncthreads();
        int v = b * 4 + (threadIdx.x >> 6);
        int u = threadIdx.x & 63;
        float acc = b0[u];
#pragma unroll 10
        for (int k = 0; k < EMB; ++k)
            acc = fmaf(emb[v * EMB + k], wx[k * UNITS + u], acc);
        embW[v * UNITS + u] = acc;
    } else {
        int e = (b - 2500) * 256 + threadIdx.x;  // 0..12287
        float v;
        if (e < 8192) {                          // K=16 frags (Wh0 / Wh1)
            int region = e >> 12;                // 0: Wh0, 1: Wh1
            int ee = e & 4095;
            int f = ee >> 8;
            int mt = f >> 2, kf = f & 3;
            int rr = ee & 255;
            int l = rr >> 2, j = rr & 3;
            int k = kf * 16 + (l >> 4) * 4 + j;
            int col = mt * 16 + (l & 15);
            v = region ? Wh1[k * UNITS + col] : Wh0[k * UNITS + col];
        } else {                                 // Wx1 K=32 frags
            int ee = e - 8192;
            int f = ee >> 9;
            int mt = f >> 1, kf = f & 1;
            int rr = ee & 511;
            int l = rr >> 3, j = rr & 7;
            int k = kf * 32 + (l >> 4) * 8 + j;
            v = Wx1[k * UNITS + mt * 16 + (l & 15)];
        }
        wfrags[e] = (_Float16)v;
    }
}

// ------------------------------ main kernel --------------------------------
// Wave B step for timestep t' (reads h0n(t') from FIFO slot SB).
#define B_BODY(SB)                                                            \
    {                                                                         \
        f16x8 hb0 = *(const f16x8*)&hfifo[SB][r][8 * q];                      \
        f16x8 hb1 = *(const f16x8*)&hfifo[SB][r][32 + 8 * q];                 \
        f32x4 bb[4], a[4];                                                    \
        _Pragma("unroll")                                                     \
        for (int mt = 0; mt < 4; ++mt) {                                      \
            bb[mt][0] = 0.f; bb[mt][1] = 0.f;                                 \
            bb[mt][2] = 0.f; bb[mt][3] = 0.f;                                 \
            a[mt] = b1v[mt];                                                  \
        }                                                                     \
        _Pragma("unroll")                                                     \
        for (int kf = 0; kf < 4; ++kf)                                        \
            _Pragma("unroll")                                                 \
            for (int mt = 0; mt < 4; ++mt)                                    \
                bb[mt] = __builtin_amdgcn_mfma_f32_16x16x16f16(               \
                    w1h[mt][kf], h1f[kf], bb[mt], 0, 0, 0);                   \
        _Pragma("unroll")                                                     \
        for (int mt = 0; mt < 4; ++mt) {                                      \
            a[mt] = __builtin_amdgcn_mfma_f32_16x16x32_f16(                   \
                w1x[mt][0], hb0, a[mt], 0, 0, 0);                             \
            a[mt] = __builtin_amdgcn_mfma_f32_16x16x32_f16(                   \
                w1x[mt][1], hb1, a[mt], 0, 0, 0);                             \
        }                                                                     \
        _Pragma("unroll")                                                     \
        for (int mt = 0; mt < 4; ++mt)                                        \
            h1f[mt] = tanh_pack(a[mt] + bb[mt]);                              \
    }

// One pipeline position: A does timestep t (writes slot SA, prefetches
// embW for t+2 via TOK2); B does t-1 (reads slot SB) when BACT.
#define RNN_STEP(TOK2, SA, SB, BACT)                                          \
    {                                                                         \
        if (wv == 0) {                                                        \
            f32x4 e2[4], acc[4];                                              \
            _Pragma("unroll")                                                 \
            for (int mt = 0; mt < 4; ++mt)                                    \
                e2[mt] = embWv[(TOK2) * 16 + mt * 4 + q];                     \
            _Pragma("unroll")                                                 \
            for (int mt = 0; mt < 4; ++mt) acc[mt] = e0[mt];                  \
            _Pragma("unroll")                                                 \
            for (int kf = 0; kf < 4; ++kf)                                    \
                _Pragma("unroll")                                             \
                for (int mt = 0; mt < 4; ++mt)                                \
                    acc[mt] = __builtin_amdgcn_mfma_f32_16x16x16f16(          \
                        w0f[mt][kf], h0f[kf], acc[mt], 0, 0, 0);              \
            _Pragma("unroll")                                                 \
            for (int mt = 0; mt < 4; ++mt) {                                  \
                h0f[mt] = tanh_pack(acc[mt]);                                 \
                *(uint2*)&hfifo[SA][r][mt * 16 + 4 * q] =                     \
                    *(const uint2*)&h0f[mt];                                  \
            }                                                                 \
            _Pragma("unroll")                                                 \
            for (int mt = 0; mt < 4; ++mt) {                                  \
                e0[mt] = e1[mt]; e1[mt] = e2[mt];                             \
            }                                                                 \
        } else if (BACT) {                                                    \
            B_BODY(SB)                                                        \
        }                                                                     \
        lds_barrier();                                                        \
    }

__global__ __launch_bounds__(128, 2) void rnn_mfma_kernel(
    const int*      __restrict__ tokens,   // [BATCH][SEQ]
    const float*    __restrict__ embW,     // [TOTAL_WORDS][UNITS]
    const _Float16* __restrict__ wfrags,   // packed f16 A-frags
    const float*    __restrict__ b1,       // [UNITS]
    const float*    __restrict__ Wout,     // [UNITS]
    const float*    __restrict__ bout,     // [1]
    float*          __restrict__ out) {    // [BATCH]
    const int tid = threadIdx.x;
    const int wv  = tid >> 6;      // 0 = producer (layer 0), 1 = consumer
    const int l   = tid & 63;
    const int r   = l & 15;        // batch row within the block's 16-row group
    const int q   = l >> 4;        // quad 0..3
    const int row0 = blockIdx.x * 16;

    // h0n FIFO: 2 slots x 16 rows x 72 f16 (64 + 8 pad -> 144B stride:
    // 16B-aligned b128 reads, bank-uniform). 4.5 KB.
    __shared__ __align__(16) _Float16 hfifo[2][16][72];

    const f16x4* wf4 = (const f16x4*)wfrags;
    const f16x8* wf8 = (const f16x8*)wfrags;
    const f32x4* embWv = (const f32x4*)embW;
    const int tokbase = (row0 + r) * SEQ;

    // per-wave state (all compile-time indexed)
    f16x4 w0f[4][4];               // A: Wh0 K=16 frags
    f16x4 w1h[4][4];               // B: Wh1 K=16 frags
    f16x8 w1x[4][2];               // B: Wx1 K=32 frags
    f16x4 h0f[4], h1f[4];
    f32x4 e0[4], e1[4], b1v[4];
    int4 tkA, tkB;

    if (wv == 0) {
#pragma unroll
        for (int mt = 0; mt < 4; ++mt)
#pragma unroll
            for (int kf = 0; kf < 4; ++kf)
                w0f[mt][kf] = wf4[(mt * 4 + kf) * 64 + l];
#pragma unroll
        for (int kf = 0; kf < 4; ++kf)
#pragma unroll
            for (int j = 0; j < 4; ++j) h0f[kf][j] = (_Float16)0.0f;
        tkA = *(const int4*)&tokens[tokbase];
        tkB = *(const int4*)&tokens[tokbase + 4];
#pragma unroll
        for (int mt = 0; mt < 4; ++mt) {
            e0[mt] = embWv[tkA.x * 16 + mt * 4 + q];
            e1[mt] = embWv[tkA.y * 16 + mt * 4 + q];
        }
    } else {
#pragma unroll
        for (int mt = 0; mt < 4; ++mt) {
#pragma unroll
            for (int kf = 0; kf < 4; ++kf)
                w1h[mt][kf] = wf4[(16 + mt * 4 + kf) * 64 + l];
#pragma unroll
            for (int kf = 0; kf < 2; ++kf)
                w1x[mt][kf] = wf8[1024 + (mt * 2 + kf) * 64 + l];
            b1v[mt] = ((const f32x4*)b1)[mt * 4 + q];
        }
#pragma unroll
        for (int kf = 0; kf < 4; ++kf)
#pragma unroll
            for (int j = 0; j < 4; ++j) h1f[kf][j] = (_Float16)0.0f;
    }

    for (int k = 0; k < SEQ / 4; ++k) {
        int4 tkC;
        if (wv == 0) {
            int off = (4 * k + 8 <= SEQ - 4) ? (4 * k + 8) : (SEQ - 4);
            tkC = *(const int4*)&tokens[tokbase + off];
        }
        bool bact0 = (k > 0);
        RNN_STEP(tkA.z, 0, 1, bact0)   // A: t=4k   B: t-1 (slot 1)
        RNN_STEP(tkA.w, 1, 0, true)    // A: t=4k+1 B: 4k   (slot 0)
        RNN_STEP(tkB.x, 0, 1, true)    // A: t=4k+2 B: 4k+1 (slot 1)
        RNN_STEP(tkB.y, 1, 0, true)    // A: t=4k+3 B: 4k+2 (slot 0)
        if (wv == 0) { tkA = tkB; tkB = tkC; }
    }

    // epilogue: B finishes t'=SEQ-1 (slot (SEQ-1)%2 = 1), then the head.
    // No barriers here (A-waves may exit).
    if (wv == 1) {
        B_BODY(1)
        float accv = 0.0f;
#pragma unroll
        for (int kf = 0; kf < 4; ++kf) {
            f32x4 wo = ((const f32x4*)Wout)[kf * 4 + q];
#pragma unroll
            for (int j = 0; j < 4; ++j)
                accv = fmaf((float)h1f[kf][j], wo[j], accv);
        }
        accv += __shfl_down(accv, 16);
        accv += __shfl_down(accv, 32);
        if (l < 16) {
            float z = accv + bout[0];
            out[row0 + r] = 1.0f / (1.0f + __expf(-z));
        }
    }
}

extern "C" void kernel_launch(void* const* d_in, const int* in_sizes, int n_in,
                              void* d_out, int out_size, void* d_ws, size_t ws_size,
                              hipStream_t stream) {
    const int*   tokens = (const int*)d_in[0];
    const float* emb    = (const float*)d_in[1];
    const float* Wx0    = (const float*)d_in[2];
    const float* Wh0    = (const float*)d_in[3];
    const float* b0     = (const float*)d_in[4];
    const float* Wx1    = (const float*)d_in[5];
    const float* Wh1    = (const float*)d_in[6];
    const float* b1     = (const float*)d_in[7];
    const float* Wout   = (const float*)d_in[8];
    const float* bout   = (const float*)d_in[9];
    float* out = (float*)d_out;

    // ws layout: embW fp32 (2,560,000 B) | packed f16 weight frags (24,576 B)
    float* embW = (float*)d_ws;
    _Float16* wfrags =
        (_Float16*)((char*)d_ws + (size_t)TOTAL_WORDS * UNITS * 4);

    prep_kernel<<<2548, 256, 0, stream>>>(emb, Wx0, b0, Wh0, Wx1, Wh1,
                                          embW, wfrags);
    rnn_mfma_kernel<<<BATCH / 16, 128, 0, stream>>>(tokens, embW, wfrags,
                                                    b1, Wout, bout, out);
}

// Round 11
// 134.318 us; speedup vs baseline: 1.2309x; 1.0154x over previous
//
#include <hip/hip_runtime.h>

// Problem constants (from reference)
#define TOTAL_WORDS 10000
#define EMB 100
#define SEQ 80
#define UNITS 64
#define BATCH 16384

// ---------------------------------------------------------------------------
// R11: all-K=32 MFMA rewrite.
//
//  KEY FINDING (R4..R10 MfmaUtil arithmetic): mfma_f32_16x16x16f16 costs the
//  SAME ~19 cyc/SIMD as mfma_f32_16x16x32_f16 on gfx950 (native shape is the
//  doubled-K one; K=16 is legacy at equal pass count). All prior rounds paid
//  K=32 price for K=16 work. This round uses 16x16x32 everywhere:
//  12 MFMAs/wave-step instead of 24 -> matrix-pipe demand halves.
//
//  - Block = 2 waves, 16 batch rows; wave p owns output units [32p, 32p+32)
//    for both layers (M-split). No divergent branches in the loop.
//  - K=32 kills the D==B register identity, so tanh'd D-frags round-trip
//    LDS: 2x ds_write_b64 + 2x ds_read_b128 per layer per wave. Row stride
//    72 f16 (144 B): 16B-aligned, bank-uniform (8 dwords/bank on b128 =
//    minimum) -> conflict-free. R9 proved the DS pipe absorbs this easily.
//  - Wh1*h1(t-1) chains hoisted before barrier #1 (independent of layer 0);
//    after the barrier only the 2-deep Wx1*h0n chains remain.
//  - embW pipeline at distance 4 with period-4 IN-PLACE register slots:
//    loop unrolled x4, each step consumes its slot as MFMA C-init and
//    reloads the same registers for t+4 -> zero rotation movs (R8-R10 spent
//    ~50 VALU/step shuffling e-registers). Tokens windowed 4-8 ahead (int4).
//  - All register arrays compile-time indexed (R5 scratch lesson).
//  - lds_barrier() = `s_waitcnt lgkmcnt(0); s_barrier`: LDS-only drain keeps
//    global prefetches in flight. Single-buffer safety: a wave reaches the
//    next write of a buffer only after a barrier that its own reads preceded
//    (lgkmcnt(0) drains them), so no parity buffers.
// ---------------------------------------------------------------------------

typedef _Float16 f16x4 __attribute__((ext_vector_type(4)));
typedef _Float16 f16x8 __attribute__((ext_vector_type(8)));
typedef _Float16 h2    __attribute__((ext_vector_type(2)));
typedef __fp16   fp16x2r __attribute__((ext_vector_type(2)));  // cvt_pkrtz ret
typedef float    f32x4 __attribute__((ext_vector_type(4)));

__device__ __forceinline__ h2 pkcvt(float a, float b) {
    fp16x2r t = __builtin_amdgcn_cvt_pkrtz(a, b);
    h2 o; o[0] = (_Float16)t[0]; o[1] = (_Float16)t[1];
    return o;
}

__device__ __forceinline__ h2 tanh_h2(h2 x) {
    // odd deg-5 in packed f16: |x| <= ~0.3 -> added err ~2e-4
    const _Float16 c3 = (_Float16)(-0.33333333f);
    const _Float16 c5 = (_Float16)(0.13333333f);
    h2 x2 = x * x;
    h2 p  = x2 * c5 + c3;     // v_pk_fma_f16
    h2 x3 = x2 * x;
    return x3 * p + x;        // v_pk_fma_f16
}

__device__ __forceinline__ f16x4 tanh_pack(f32x4 a) {
    h2 lo = tanh_h2(pkcvt(a[0], a[1]));
    h2 hi = tanh_h2(pkcvt(a[2], a[3]));
    f16x4 o;
    o[0] = lo[0]; o[1] = lo[1]; o[2] = hi[0]; o[3] = hi[1];
    return o;
}

// LDS-only barrier: drains ds ops, leaves global loads in flight.
__device__ __forceinline__ void lds_barrier() {
    asm volatile("s_waitcnt lgkmcnt(0)\n\ts_barrier" ::: "memory");
}

// ------------------- fused prologue: embW + weight packing -----------------
// blocks [0,2500): embW rows (4 per block), Wx0 staged in LDS.
// blocks [2500,2548): pack K=32 A-frags for Wh0 / Wx1 / Wh1 (8 frags each,
// 512 f16 per frag). Frag(mat, f=mt*2+kf) elem (lane l, j<8) =
//   W[kf*32 + (l>>4)*8 + j][mt*16 + (l&15)]    (layout verified in R2)
__global__ void prep_kernel(const float* __restrict__ emb,
                            const float* __restrict__ Wx0,
                            const float* __restrict__ b0,
                            const float* __restrict__ Wh0,
                            const float* __restrict__ Wx1,
                            const float* __restrict__ Wh1,
                            float* __restrict__ embW,
                            _Float16* __restrict__ wfrags) {
    int b = blockIdx.x;
    if (b < 2500) {
        __shared__ float wx[EMB * UNITS];  // 25.6 KB
        for (int i = threadIdx.x; i < EMB * UNITS; i += 256)
            wx[i] = Wx0[i];
        __syncthreads();
        int v = b * 4 + (threadIdx.x >> 6);
        int u = threadIdx.x & 63;
        float acc = b0[u];
#pragma unroll 10
        for (int k = 0; k < EMB; ++k)
            acc = fmaf(emb[v * EMB + k], wx[k * UNITS + u], acc);
        embW[v * UNITS + u] = acc;
    } else {
        int e = (b - 2500) * 256 + threadIdx.x;  // 0..12287
        int mat = e >> 12;                       // 0: Wh0, 1: Wx1, 2: Wh1
        int ee = e & 4095;
        int f = ee >> 9;                         // frag 0..7
        int mt = f >> 1, kf = f & 1;
        int rr = ee & 511;
        int l = rr >> 3, j = rr & 7;
        int k = kf * 32 + (l >> 4) * 8 + j;
        int col = mt * 16 + (l & 15);
        const float* W = (mat == 0) ? Wh0 : (mat == 1) ? Wx1 : Wh1;
        wfrags[e] = (_Float16)W[k * UNITS + col];
    }
}

// ------------------------------ main kernel --------------------------------
// One timestep. EA/EB: this step's in-place embW slot (consumed as C-init,
// reloaded for t+4). T4: token for t+4 (compile-time int4 component).
#define RNN_STEP(EA, EB, T4)                                                  \
    {                                                                         \
        f32x4 a0 = EA, a1 = EB;            /* layer-0 C-init (b0 folded) */   \
        f32x4 c0 = b1v0, c1 = b1v1;        /* layer-1 C-init (b1) */          \
        a0 = __builtin_amdgcn_mfma_f32_16x16x32_f16(w0[0][0], h0f0, a0,0,0,0);\
        a1 = __builtin_amdgcn_mfma_f32_16x16x32_f16(w0[1][0], h0f0, a1,0,0,0);\
        c0 = __builtin_amdgcn_mfma_f32_16x16x32_f16(wh[0][0], h1f0, c0,0,0,0);\
        c1 = __builtin_amdgcn_mfma_f32_16x16x32_f16(wh[1][0], h1f0, c1,0,0,0);\
        a0 = __builtin_amdgcn_mfma_f32_16x16x32_f16(w0[0][1], h0f1, a0,0,0,0);\
        a1 = __builtin_amdgcn_mfma_f32_16x16x32_f16(w0[1][1], h0f1, a1,0,0,0);\
        c0 = __builtin_amdgcn_mfma_f32_16x16x32_f16(wh[0][1], h1f1, c0,0,0,0);\
        c1 = __builtin_amdgcn_mfma_f32_16x16x32_f16(wh[1][1], h1f1, c1,0,0,0);\
        EA = embWv[(T4) * 16 + (2 * p) * 4 + q];      /* reload for t+4 */    \
        EB = embWv[(T4) * 16 + (2 * p + 1) * 4 + q];                          \
        {                                                                     \
            f16x4 n0 = tanh_pack(a0), n1 = tanh_pack(a1);                     \
            *(uint2*)&hbuf0[r][(2 * p) * 16 + 4 * q] = *(const uint2*)&n0;    \
            *(uint2*)&hbuf0[r][(2 * p + 1) * 16 + 4 * q] = *(const uint2*)&n1;\
        }                                                                     \
        lds_barrier();                                                        \
        h0f0 = *(const f16x8*)&hbuf0[r][8 * q];                               \
        h0f1 = *(const f16x8*)&hbuf0[r][32 + 8 * q];                          \
        c0 = __builtin_amdgcn_mfma_f32_16x16x32_f16(wx[0][0], h0f0, c0,0,0,0);\
        c1 = __builtin_amdgcn_mfma_f32_16x16x32_f16(wx[1][0], h0f0, c1,0,0,0);\
        c0 = __builtin_amdgcn_mfma_f32_16x16x32_f16(wx[0][1], h0f1, c0,0,0,0);\
        c1 = __builtin_amdgcn_mfma_f32_16x16x32_f16(wx[1][1], h0f1, c1,0,0,0);\
        {                                                                     \
            f16x4 n0 = tanh_pack(c0), n1 = tanh_pack(c1);                     \
            *(uint2*)&hbuf1[r][(2 * p) * 16 + 4 * q] = *(const uint2*)&n0;    \
            *(uint2*)&hbuf1[r][(2 * p + 1) * 16 + 4 * q] = *(const uint2*)&n1;\
        }                                                                     \
        lds_barrier();                                                        \
        h1f0 = *(const f16x8*)&hbuf1[r][8 * q];                               \
        h1f1 = *(const f16x8*)&hbuf1[r][32 + 8 * q];                          \
    }

__global__ __launch_bounds__(128, 2) void rnn_mfma_kernel(
    const int*      __restrict__ tokens,   // [BATCH][SEQ]
    const float*    __restrict__ embW,     // [TOTAL_WORDS][UNITS]
    const _Float16* __restrict__ wfrags,   // packed f16 K=32 A-frags
    const float*    __restrict__ b1,       // [UNITS]
    const float*    __restrict__ Wout,     // [UNITS]
    const float*    __restrict__ bout,     // [1]
    float*          __restrict__ out) {    // [BATCH]
    const int tid = threadIdx.x;
    const int p   = tid >> 6;      // wave 0/1: owns units [32p, 32p+32)
    const int l   = tid & 63;
    const int r   = l & 15;        // batch row within the block's 16-row group
    const int q   = l >> 4;        // quad 0..3
    const int row0 = blockIdx.x * 16;

    // h-state buffers, stride 72 f16 = 144 B (16B-aligned, bank-uniform)
    __shared__ __align__(16) _Float16 hbuf0[16][72];
    __shared__ __align__(16) _Float16 hbuf1[16][72];

    // this wave's K=32 weight frags: j = tile within wave (mt = 2p + j)
    const f16x8* wf8 = (const f16x8*)wfrags;
    f16x8 w0[2][2], wx[2][2], wh[2][2];
#pragma unroll
    for (int j = 0; j < 2; ++j)
#pragma unroll
        for (int kf = 0; kf < 2; ++kf) {
            int mt = 2 * p + j;
            w0[j][kf] = wf8[(mt * 2 + kf) * 64 + l];        // Wh0
            wx[j][kf] = wf8[(8 + mt * 2 + kf) * 64 + l];    // Wx1
            wh[j][kf] = wf8[(16 + mt * 2 + kf) * 64 + l];   // Wh1
        }

    const f32x4 b1v0 = ((const f32x4*)b1)[(2 * p) * 4 + q];
    const f32x4 b1v1 = ((const f32x4*)b1)[(2 * p + 1) * 4 + q];

    // hidden state as K=32 B-frags (full 64 units each)
    f16x8 h0f0, h0f1, h1f0, h1f1;
#pragma unroll
    for (int j = 0; j < 8; ++j) {
        h0f0[j] = (_Float16)0.0f; h0f1[j] = (_Float16)0.0f;
        h1f0[j] = (_Float16)0.0f; h1f1[j] = (_Float16)0.0f;
    }

    const f32x4* embWv = (const f32x4*)embW;
    const int tokbase = (row0 + r) * SEQ;

    // embW slots for t=0..3 (period-4 in-place pipeline)
    int4 tk0 = *(const int4*)&tokens[tokbase];
    int4 tk  = *(const int4*)&tokens[tokbase + 4];   // window: t+4..t+7
    f32x4 e0a = embWv[tk0.x * 16 + (2 * p) * 4 + q];
    f32x4 e0b = embWv[tk0.x * 16 + (2 * p + 1) * 4 + q];
    f32x4 e1a = embWv[tk0.y * 16 + (2 * p) * 4 + q];
    f32x4 e1b = embWv[tk0.y * 16 + (2 * p + 1) * 4 + q];
    f32x4 e2a = embWv[tk0.z * 16 + (2 * p) * 4 + q];
    f32x4 e2b = embWv[tk0.z * 16 + (2 * p + 1) * 4 + q];
    f32x4 e3a = embWv[tk0.w * 16 + (2 * p) * 4 + q];
    f32x4 e3b = embWv[tk0.w * 16 + (2 * p + 1) * 4 + q];

    for (int k = 0; k < SEQ / 4; ++k) {
        // token window for t+8..t+11 (clamped tail: feeds only dead loads)
        int off = (4 * k + 8 <= SEQ - 4) ? (4 * k + 8) : (SEQ - 4);
        int4 tkC = *(const int4*)&tokens[tokbase + off];

        RNN_STEP(e0a, e0b, tk.x)   // t = 4k
        RNN_STEP(e1a, e1b, tk.y)   // t = 4k+1
        RNN_STEP(e2a, e2b, tk.z)   // t = 4k+2
        RNN_STEP(e3a, e3b, tk.w)   // t = 4k+3

        tk = tkC;
    }

    // ---- output head: out[row] = sigmoid(h1 . Wout + bout) ----
    // h1f0[j] = h1[r][8q+j], h1f1[j] = h1[r][32+8q+j]; both waves hold the
    // full state, wave 0 stores.
    if (p == 0) {
        f32x4 wo0 = ((const f32x4*)Wout)[2 * q];
        f32x4 wo1 = ((const f32x4*)Wout)[2 * q + 1];
        f32x4 wo2 = ((const f32x4*)Wout)[8 + 2 * q];
        f32x4 wo3 = ((const f32x4*)Wout)[8 + 2 * q + 1];
        float accv = 0.0f;
#pragma unroll
        for (int j = 0; j < 4; ++j) {
            accv = fmaf((float)h1f0[j],     wo0[j], accv);
            accv = fmaf((float)h1f0[4 + j], wo1[j], accv);
            accv = fmaf((float)h1f1[j],     wo2[j], accv);
            accv = fmaf((float)h1f1[4 + j], wo3[j], accv);
        }
        accv += __shfl_down(accv, 16);
        accv += __shfl_down(accv, 32);
        if (l < 16) {
            float z = accv + bout[0];
            out[row0 + r] = 1.0f / (1.0f + __expf(-z));
        }
    }
}

extern "C" void kernel_launch(void* const* d_in, const int* in_sizes, int n_in,
                              void* d_out, int out_size, void* d_ws, size_t ws_size,
                              hipStream_t stream) {
    const int*   tokens = (const int*)d_in[0];
    const float* emb    = (const float*)d_in[1];
    const float* Wx0    = (const float*)d_in[2];
    const float* Wh0    = (const float*)d_in[3];
    const float* b0     = (const float*)d_in[4];
    const float* Wx1    = (const float*)d_in[5];
    const float* Wh1    = (const float*)d_in[6];
    const float* b1     = (const float*)d_in[7];
    const float* Wout   = (const float*)d_in[8];
    const float* bout   = (const float*)d_in[9];
    float* out = (float*)d_out;

    // ws layout: embW fp32 (2,560,000 B) | packed f16 weight frags (24,576 B)
    float* embW = (float*)d_ws;
    _Float16* wfrags =
        (_Float16*)((char*)d_ws + (size_t)TOTAL_WORDS * UNITS * 4);

    prep_kernel<<<2548, 256, 0, stream>>>(emb, Wx0, b0, Wh0, Wx1, Wh1,
                                          embW, wfrags);
    rnn_mfma_kernel<<<BATCH / 16, 128, 0, stream>>>(tokens, embW, wfrags,
                                                    b1, Wout, bout, out);
}